// Round 8
// baseline (174.982 us; speedup 1.0000x reference)
//
#include <hip/hip_runtime.h>

#define N_NODES 100000
#define N_EDGES 1600000
#define EPS 1e-5f
#define CHUNK_STRIDE (N_NODES * 8)   // f16 elements per column-chunk sub-table

typedef __bf16    bf16x8 __attribute__((ext_vector_type(8)));
typedef _Float16  f16x2  __attribute__((ext_vector_type(2)));
typedef _Float16  f16x8  __attribute__((ext_vector_type(8)));
typedef float     f32x4  __attribute__((ext_vector_type(4)));
typedef unsigned int u32;
typedef u32       u32x4  __attribute__((ext_vector_type(4)));

__device__ __forceinline__ u32 pkmax(u32 a, u32 b) {
  u32 d; asm("v_pk_max_f16 %0,%1,%2" : "=v"(d) : "v"(a), "v"(b)); return d;
}
__device__ __forceinline__ u32 pkmin(u32 a, u32 b) {
  u32 d; asm("v_pk_min_f16 %0,%1,%2" : "=v"(d) : "v"(a), "v"(b)); return d;
}
// c + lo(v) + hi(v)   (f16 halves, f32 accumulate)
__device__ __forceinline__ float halves_sum(u32 v, float c) {
  f16x2 p = __builtin_bit_cast(f16x2, v);
#if __has_builtin(__builtin_amdgcn_fdot2)
  f16x2 one2 = {(_Float16)1.0f, (_Float16)1.0f};
  return __builtin_amdgcn_fdot2(p, one2, c, false);
#else
  return c + (float)p[0] + (float)p[1];
#endif
}
// c + lo(v)^2 + hi(v)^2
__device__ __forceinline__ float halves_sq(u32 v, float c) {
  f16x2 p = __builtin_bit_cast(f16x2, v);
#if __has_builtin(__builtin_amdgcn_fdot2)
  return __builtin_amdgcn_fdot2(p, p, c, false);
#else
  float a = (float)p[0], b = (float)p[1];
  return fmaf(a, a, fmaf(b, b, c));
#endif
}

// ---------------------------------------------------------------------------
// Kernel 0: per-node GEMM  g[v] = W_f . feat[v] + W_n . node[v]   (f16 out),
// stored COLUMN-CHUNK-MAJOR: g[cb][node][j], cb = d>>3, j = d&7.
// One wave per 16 nodes, 12 MFMAs. Block 0 zeroes the 8x128 replicated
// stats accumulators (gather, launched later, adds into them).
// ---------------------------------------------------------------------------
__global__ __launch_bounds__(256) void gemm_kernel(
    const float* __restrict__ nodep, const float* __restrict__ feat,
    const float* __restrict__ W, unsigned short* __restrict__ g,
    float* __restrict__ accum) {
  if (blockIdx.x == 0) {
    for (int k = threadIdx.x; k < 1024; k += 256) accum[k] = 0.f;
  }
  const int lane = threadIdx.x & 63;
  const int wave = (int)((blockIdx.x * blockDim.x + threadIdx.x) >> 6);
  const int c    = lane & 15;
  const int quad = lane >> 4;
  if (wave >= N_NODES / 16) return;   // 6250 groups

  bf16x8 Bfrag[4][3];
#pragma unroll
  for (int t = 0; t < 4; ++t) {
    const float* wrow = W + (t * 16 + c) * 67;
#pragma unroll
    for (int s2 = 0; s2 < 3; ++s2) {
#pragma unroll
      for (int j = 0; j < 8; ++j) {
        int k = s2 * 32 + quad * 8 + j;
        Bfrag[t][s2][j] = (k < 67) ? (__bf16)wrow[k] : (__bf16)0.0f;
      }
    }
  }

  const int v = wave * 16 + c;
  const f32x4* f4 = (const f32x4*)(feat + (size_t)v * 64 + quad * 8);
  f32x4 fa = f4[0], fb = f4[1];
  const f32x4* f4b = (const f32x4*)(feat + (size_t)v * 64 + 32 + quad * 8);
  f32x4 fc = f4b[0], fd = f4b[1];
  bf16x8 A0, A1;
#pragma unroll
  for (int j = 0; j < 4; ++j) {
    A0[j] = (__bf16)fa[j]; A0[j + 4] = (__bf16)fb[j];
    A1[j] = (__bf16)fc[j]; A1[j + 4] = (__bf16)fd[j];
  }
  bf16x8 A2;
#pragma unroll
  for (int j = 0; j < 8; ++j) A2[j] = (__bf16)0.0f;
  if (quad == 0) {
    const float* np = nodep + (size_t)v * 3;
    A2[0] = (__bf16)np[0];
    A2[1] = (__bf16)np[1];
    A2[2] = (__bf16)np[2];
  }

#pragma unroll
  for (int t = 0; t < 4; ++t) {
    f32x4 acc = {0.f, 0.f, 0.f, 0.f};
    acc = __builtin_amdgcn_mfma_f32_16x16x32_bf16(A0, Bfrag[t][0], acc, 0, 0, 0);
    acc = __builtin_amdgcn_mfma_f32_16x16x32_bf16(A1, Bfrag[t][1], acc, 0, 0, 0);
    acc = __builtin_amdgcn_mfma_f32_16x16x32_bf16(A2, Bfrag[t][2], acc, 0, 0, 0);
    // store chunk-major: d = t*16+c -> chunk cb = d>>3, col j = d&7
    const int d = t * 16 + c;
    unsigned short* gp = g + (size_t)(d >> 3) * CHUNK_STRIDE
                           + (size_t)(wave * 16 + quad * 4) * 8 + (d & 7);
#pragma unroll
    for (int r = 0; r < 4; ++r)
      gp[r * 8] = __builtin_bit_cast(unsigned short, (_Float16)acc[r]);
  }
}

// ---------------------------------------------------------------------------
// Kernel 1: gather-reduce, XCD-pinned column chunks.
// Block handles chunk cb = blockIdx&7 for 256 consecutive nodes; blockIdx%8
// round-robins over XCDs [m09], so XCD k only ever gathers from sub-table k
// (1.6 MB -> L2-resident). Each lane owns one node: 16 independent 16B row
// gathers; max/min/sum/sumsq reduced in-register over the 16 edges;
// per-node c-fold (c = Wn . node_i, cols cb*8..+7):
//   sh += Sn - 16c ;  sq += sqg - 2c*Sn + 16c^2
// gmax/gmin stored chunk-major -> fully coalesced 1KB wave stores.
// Epilogue: 64-lane shfl sum -> LDS -> atomicAdd into 1 of 8 banks.
// ---------------------------------------------------------------------------
__global__ __launch_bounds__(256) void gather_kernel(
    const float* __restrict__ nodep, const int* __restrict__ edges,
    const unsigned short* __restrict__ g, const float* __restrict__ W,
    _Float16* __restrict__ gmax, _Float16* __restrict__ gmin,
    float* __restrict__ accum) {
  const int tid  = (int)threadIdx.x;
  const int lane = tid & 63;
  const int cb   = (int)(blockIdx.x & 7);
  const int i    = (int)(blockIdx.x >> 3) * 256 + tid;

  __shared__ float wnl[24];
  __shared__ float sred[4][16];
  if (tid < 8) {
    const int col = cb * 8 + tid;
    wnl[3 * tid]     = W[col * 67 + 64];
    wnl[3 * tid + 1] = W[col * 67 + 65];
    wnl[3 * tid + 2] = W[col * 67 + 66];
  }
  __syncthreads();

  float sh[8], sq[8];
#pragma unroll
  for (int j = 0; j < 8; ++j) { sh[j] = 0.f; sq[j] = 0.f; }

  if (i < N_NODES) {
    // 16 edge-dst indices (src[e] = e % N => edge k of node i is i + k*N)
    int idx[16];
    const int* ep = edges + 2 * i + 1;
#pragma unroll
    for (int k = 0; k < 16; ++k) idx[k] = ep[2 * k * N_NODES];
    // 16 independent 16B gathers from this XCD's 1.6MB sub-table
    const unsigned short* gt = g + (size_t)cb * CHUNK_STRIDE;
    u32x4 r[16];
#pragma unroll
    for (int k = 0; k < 16; ++k)
      r[k] = *(const u32x4*)(gt + (size_t)idx[k] * 8);

    const float* np = nodep + (size_t)i * 3;
    const float nx = np[0], ny = np[1], nz = np[2];

    float Sn[8], sqg[8];
#pragma unroll
    for (int j = 0; j < 8; ++j) { Sn[j] = 0.f; sqg[j] = 0.f; }
    u32 mx[4], mn[4];
#pragma unroll
    for (int p = 0; p < 8; ++p) {
      const u32x4 va = r[2 * p], vb = r[2 * p + 1];
#pragma unroll
      for (int q = 0; q < 4; ++q) {
        u32 m  = pkmax(va[q], vb[q]);
        u32 n2 = pkmin(va[q], vb[q]);
        if (p == 0) { mx[q] = m; mn[q] = n2; }
        else        { mx[q] = pkmax(mx[q], m); mn[q] = pkmin(mn[q], n2); }
        u32 plo = __builtin_amdgcn_perm(va[q], vb[q], 0x01000504u); // col 2q
        u32 phi = __builtin_amdgcn_perm(va[q], vb[q], 0x03020706u); // col 2q+1
        Sn[2 * q]      = halves_sum(plo, Sn[2 * q]);
        Sn[2 * q + 1]  = halves_sum(phi, Sn[2 * q + 1]);
        sqg[2 * q]     = halves_sq(plo, sqg[2 * q]);
        sqg[2 * q + 1] = halves_sq(phi, sqg[2 * q + 1]);
      }
    }
    // chunk-major stores: lane-consecutive nodes -> 1KB contiguous per wave
    u32x4 wm = {mx[0], mx[1], mx[2], mx[3]};
    *(u32x4*)(gmax + (size_t)cb * CHUNK_STRIDE + (size_t)i * 8) = wm;
    u32x4 wn4 = {mn[0], mn[1], mn[2], mn[3]};
    *(u32x4*)(gmin + (size_t)cb * CHUNK_STRIDE + (size_t)i * 8) = wn4;
    // per-node c-fold
#pragma unroll
    for (int j = 0; j < 8; ++j) {
      const float* wp = wnl + 3 * j;
      float cj = fmaf(wp[2], nz, fmaf(wp[1], ny, wp[0] * nx));
      sh[j] = Sn[j] - 16.f * cj;
      sq[j] = sqg[j] + cj * fmaf(16.f, cj, -2.f * Sn[j]);
    }
  }

  // 64-lane sum (all threads participate; i>=N contributes zeros)
#pragma unroll
  for (int step = 1; step < 64; step <<= 1) {
#pragma unroll
    for (int j = 0; j < 8; ++j) {
      sh[j] += __shfl_xor(sh[j], step, 64);
      sq[j] += __shfl_xor(sq[j], step, 64);
    }
  }
  const int w = tid >> 6;
  if (lane == 0) {
#pragma unroll
    for (int j = 0; j < 8; ++j) { sred[w][j] = sh[j]; sred[w][8 + j] = sq[j]; }
  }
  __syncthreads();
  if (tid < 16) {
    float v = (sred[0][tid] + sred[1][tid]) + (sred[2][tid] + sred[3][tid]);
    const int col = cb * 8 + (tid & 7);
    const int off = (tid < 8) ? col : (64 + col);
    atomicAdd(accum + 128 * ((int)(blockIdx.x >> 3) & 7) + off, v);
  }
}

// ---------------------------------------------------------------------------
// Kernel 2: finalize. Thread q handles (node i = q>>3, chunk cb = q&7):
// reads 16B chunk-major gmax/gmin, writes 32B node-major out (fully
// coalesced). out[i][d] = relu((sel - c_i[d])*sc[d] + sh[d]); sel = gmax if
// sc>=0 else gmin (relu(affine(.)) is monotone per column).
// ---------------------------------------------------------------------------
__global__ __launch_bounds__(256) void finalize_kernel(
    const _Float16* __restrict__ gmax, const _Float16* __restrict__ gmin,
    const float* __restrict__ accum, const float* __restrict__ gamma,
    const float* __restrict__ beta, const float* __restrict__ nodep,
    const float* __restrict__ W, float* __restrict__ out) {
  __shared__ __align__(16) float ssl[128];
  __shared__ float wnl[192];
  const int t = threadIdx.x;
  if (t < 64) {
    float a = 0.f, b = 0.f;
#pragma unroll
    for (int rp = 0; rp < 8; ++rp) {
      a += accum[rp * 128 + t];
      b += accum[rp * 128 + 64 + t];
    }
    const float inv_ne = 1.0f / (float)N_EDGES;
    float mean = a * inv_ne;
    float var  = fmaxf(b * inv_ne - mean * mean, 0.f);
    float sc   = gamma[t] * rsqrtf(var + EPS);
    ssl[t]      = sc;
    ssl[64 + t] = beta[t] - mean * sc;
    wnl[3 * t]     = W[t * 67 + 64];
    wnl[3 * t + 1] = W[t * 67 + 65];
    wnl[3 * t + 2] = W[t * 67 + 66];
  }
  __syncthreads();

  const int q  = (int)(blockIdx.x * 256) + t;   // < 800,000
  const int i  = q >> 3, cb = q & 7, d0 = cb * 8;
  const float nx = nodep[3 * i], ny = nodep[3 * i + 1], nz = nodep[3 * i + 2];
  f32x4 sc0 = *(const f32x4*)&ssl[d0];
  f32x4 sc1 = *(const f32x4*)&ssl[d0 + 4];
  bool needmax = (sc0[0] >= 0.f) | (sc0[1] >= 0.f) | (sc0[2] >= 0.f) |
                 (sc0[3] >= 0.f) | (sc1[0] >= 0.f) | (sc1[1] >= 0.f) |
                 (sc1[2] >= 0.f) | (sc1[3] >= 0.f);
  bool needmin = (sc0[0] < 0.f) | (sc0[1] < 0.f) | (sc0[2] < 0.f) |
                 (sc0[3] < 0.f) | (sc1[0] < 0.f) | (sc1[1] < 0.f) |
                 (sc1[2] < 0.f) | (sc1[3] < 0.f);
  f16x8 gx = {}, gn = {};
  if (needmax) gx = *(const f16x8*)(gmax + (size_t)cb * CHUNK_STRIDE + (size_t)i * 8);
  if (needmin) gn = *(const f16x8*)(gmin + (size_t)cb * CHUNK_STRIDE + (size_t)i * 8);
  f32x4 o0, o1;
#pragma unroll
  for (int j = 0; j < 8; ++j) {
    const int d = d0 + j;
    float sc = (j < 4) ? sc0[j] : sc1[j - 4];
    float shf = ssl[64 + d];
    float v = (sc >= 0.f) ? (float)gx[j] : (float)gn[j];
    float c = fmaf(wnl[3 * d + 2], nz, fmaf(wnl[3 * d + 1], ny, wnl[3 * d] * nx));
    float r = fmaxf(fmaf(v - c, sc, shf), 0.f);
    if (j < 4) o0[j] = r; else o1[j - 4] = r;
  }
  float* op = out + (size_t)i * 64 + d0;
  *(f32x4*)op       = o0;
  *(f32x4*)(op + 4) = o1;
}

// ---------------------------------------------------------------------------
extern "C" void kernel_launch(void* const* d_in, const int* in_sizes, int n_in,
                              void* d_out, int out_size, void* d_ws, size_t ws_size,
                              hipStream_t stream) {
  const float* nodep = (const float*)d_in[0];
  const float* feat  = (const float*)d_in[1];
  const float* W     = (const float*)d_in[2];
  const float* gamma = (const float*)d_in[3];
  const float* beta  = (const float*)d_in[4];
  const int*   edges = (const int*)d_in[5];

  // workspace layout (16B-aligned; total 38,404,096 B)
  char* ws = (char*)d_ws;
  unsigned short* g = (unsigned short*)ws;                    // 12,800,000 B
  _Float16* gmax = (_Float16*)(ws + 12800000);                // 12,800,000 B
  _Float16* gmin = (_Float16*)(ws + 25600000);                // 12,800,000 B
  float* accum   = (float*)(ws + 38400000);                   //     4,096 B
  float* out     = (float*)d_out;

  gemm_kernel<<<1563, 256, 0, stream>>>(nodep, feat, W, g, accum);
  gather_kernel<<<8 * ((N_NODES + 255) / 256), 256, 0, stream>>>(
      nodep, edges, g, W, gmax, gmin, accum);
  finalize_kernel<<<(N_NODES * 8) / 256, 256, 0, stream>>>(
      gmax, gmin, accum, gamma, beta, nodep, W, out);
}